// Round 1
// baseline (262.627 us; speedup 1.0000x reference)
//
#include <hip/hip_runtime.h>
#include <hip/hip_bf16.h>

// DeepFM constants
#define BATCH 16384
#define FIELD 39
#define EMB 32
#define DIN 1248               // FIELD*EMB
#define K1P 1280               // padded K for GEMM1 (10*128)
#define HID 400
#define K2P 512                // padded K for GEMM2 (4*128) -- was 448/BK64;
                               // BK=128 halves barrier drains in GEMM2
#define NPAD 512               // padded N for both GEMMs

typedef __attribute__((ext_vector_type(8))) short short8;     // 8 bf16 = 4 VGPRs
typedef __attribute__((ext_vector_type(16))) float float16v;  // 32x32 MFMA C/D
typedef __attribute__((ext_vector_type(4))) float float4c;    // clang vec (nontemporal ok)

static __device__ __forceinline__ unsigned short f2bf(float f) {
    __hip_bfloat16 h = __float2bfloat16(f);  // RNE
    return *(unsigned short*)&h;
}

// ---------------------------------------------------------------------------
// Kernel 1 (prep): block-range-split combo.
//   blocks [0, 4096): wave-per-row gather: emb (bf16, stride K1P, zero-padded),
//     first_order, second_order, AND out0[r] = fb + fo.fW + so.fW.
//   blocks [4096, ...): weight cvt fp32->bf16 with zero padding.
// ---------------------------------------------------------------------------
#define CVT_ELEMS (NPAD * K1P + NPAD * K2P + 2 * NPAD)
#define GATHER_BLOCKS (BATCH / 4)

__global__ __launch_bounds__(256) void prep_kernel(
    const int* __restrict__ feat_index,
    const float* __restrict__ feat_value,
    const float* __restrict__ emb_table,
    const float* __restrict__ bias_table,
    const float* __restrict__ W1, const float* __restrict__ b1,
    const float* __restrict__ W2, const float* __restrict__ b2,
    const float* __restrict__ fW, const float* __restrict__ fb,
    unsigned short* __restrict__ emb_ws,   // BATCH x K1P (bf16)
    unsigned short* __restrict__ W1b,      // NPAD x K1P
    unsigned short* __restrict__ W2b,      // NPAD x K2P
    float* __restrict__ b1p, float* __restrict__ b2p,
    float* __restrict__ first_order,       // BATCH x FIELD
    float* __restrict__ second_order,      // BATCH x EMB
    float* __restrict__ out0)              // BATCH
{
    if (blockIdx.x < GATHER_BLOCKS) {
        const int lane = threadIdx.x & 63;
        const int wave = threadIdx.x >> 6;
        const int r = blockIdx.x * 4 + wave;

        int   idx0 = 0;
        float val0 = 0.f;
        float s1 = 0.f;
        if (lane < FIELD) {
            idx0 = feat_index[r * FIELD + lane];
            val0 = feat_value[r * FIELD + lane];
            float fov = bias_table[idx0] * val0;
            __builtin_nontemporal_store(fov, first_order + r * FIELD + lane);
            s1 = fov * fW[lane];
        }

        const int fsub = lane >> 3;
        const int j4   = (lane & 7) * 4;

        float sx = 0.f, sy = 0.f, sz = 0.f, sw = 0.f;
        float qx = 0.f, qy = 0.f, qz = 0.f, qw = 0.f;

        #pragma unroll
        for (int step = 0; step < 5; ++step) {
            const int   f  = step * 8 + fsub;
            const int   fi = __shfl(idx0, f, 64);
            const float fv = __shfl(val0, f, 64);
            float4 e4 = make_float4(0.f, 0.f, 0.f, 0.f);
            if (f < FIELD) {
                float4 t = *(const float4*)(emb_table + (size_t)fi * EMB + j4);
                e4.x = t.x * fv; e4.y = t.y * fv; e4.z = t.z * fv; e4.w = t.w * fv;
                uint2 pk;
                pk.x = (unsigned)f2bf(e4.x) | ((unsigned)f2bf(e4.y) << 16);
                pk.y = (unsigned)f2bf(e4.z) | ((unsigned)f2bf(e4.w) << 16);
                *(uint2*)(emb_ws + (size_t)r * K1P + step * 256 + lane * 4) = pk;
            }
            sx += e4.x; sy += e4.y; sz += e4.z; sw += e4.w;
            qx += e4.x * e4.x; qy += e4.y * e4.y; qz += e4.z * e4.z; qw += e4.w * e4.w;
        }

        if (lane < 8) {
            uint2 z; z.x = 0u; z.y = 0u;
            *(uint2*)(emb_ws + (size_t)r * K1P + DIN + lane * 4) = z;
        }

        #pragma unroll
        for (int d = 8; d < 64; d <<= 1) {
            sx += __shfl_xor(sx, d, 64); sy += __shfl_xor(sy, d, 64);
            sz += __shfl_xor(sz, d, 64); sw += __shfl_xor(sw, d, 64);
            qx += __shfl_xor(qx, d, 64); qy += __shfl_xor(qy, d, 64);
            qz += __shfl_xor(qz, d, 64); qw += __shfl_xor(qw, d, 64);
        }

        float s2 = 0.f;
        if (lane < 8) {
            float4c so4;
            so4.x = 0.5f * (sx * sx - qx);
            so4.y = 0.5f * (sy * sy - qy);
            so4.z = 0.5f * (sz * sz - qz);
            so4.w = 0.5f * (sw * sw - qw);
            __builtin_nontemporal_store(so4,
                (float4c*)(second_order + (size_t)r * EMB + lane * 4));
            const float* fw = fW + FIELD + lane * 4;
            s2 = so4.x * fw[0] + so4.y * fw[1] + so4.z * fw[2] + so4.w * fw[3];
        }

        float s = s1 + s2;
        #pragma unroll
        for (int d = 1; d < 64; d <<= 1)
            s += __shfl_xor(s, d, 64);
        if (lane == 0)
            out0[r] = s + fb[0];
    } else {
        int i = (blockIdx.x - GATHER_BLOCKS) * 256 + threadIdx.x;
        const int n1p = NPAD * K1P;
        const int n2p = NPAD * K2P;
        if (i < n1p) {
            int row = i / K1P, col = i - row * K1P;
            W1b[i] = (row < HID && col < DIN)
                   ? f2bf(W1[row * DIN + col]) : (unsigned short)0;
        } else if (i < n1p + n2p) {
            int j = i - n1p;
            int row = j / K2P, col = j - row * K2P;
            W2b[j] = (row < HID && col < HID)
                   ? f2bf(W2[row * HID + col]) : (unsigned short)0;
        } else if (i < n1p + n2p + NPAD) {
            int k = i - n1p - n2p;
            b1p[k] = (k < HID) ? b1[k] : 0.f;
        } else if (i < n1p + n2p + 2 * NPAD) {
            int k = i - n1p - n2p - NPAD;
            b2p[k] = (k < HID) ? b2[k] : 0.f;
        }
    }
}

// ---------------------------------------------------------------------------
// MFMA NT-GEMM on v_mfma_f32_32x32x16_bf16 (2382-2495 TF ceiling vs 2075 for
// 16x16x32 -- 18% cheaper issue for identical LDS traffic).
// BK=128 for both GEMMs now (K2 padded 448->512): GEMM2 drops from 7 to 4
// barrier-drain pairs -- it was drain-bound (16 MFMA = ~128 cyc of math
// between ~800-cyc vmcnt(0)+barrier drains).
// m97-pattern gll staging, XOR chunk swizzle. C = relu(A * Bw^T + bias);
// Bw is NPAD x K padded/guard-free.
// Per wave: 64x64 = 2x2 tiles of 32x32; acc = 4 x float16v.
// Layouts (m74/m101-verified): A: m=lane&31, k=(lane>>5)*8+j; B mirrored;
// C/D: col=lane&31, row=(reg&3)+8*(reg>>2)+4*(lane>>5).
// cn = compute-limit (waves fully right of cn skip staging+MFMA, store 0s),
// stn = store-limit. Separating them lets GEMM1 store finite zeros into
// h1's K-padding columns (needed: ws is poison; W2b zero-cols make the
// VALUES irrelevant but they must not be NaN) without paying MFMA for them.
// FINAL_DOT fuses C-row . fW into out0.
// ---------------------------------------------------------------------------
template<int BK, bool OUT_BF16, bool FINAL_DOT>
__global__ __launch_bounds__(256) void gemm_mfma(
    const unsigned short* __restrict__ A, int lda,
    const unsigned short* __restrict__ Bw, int ldb,
    const float* __restrict__ bias,
    void* __restrict__ Cp, int ldc, int stn, int cn, int K,
    const float* __restrict__ fW, float* __restrict__ out0)
{
    constexpr int BM = 128, BN = 128;
    constexpr int CH  = BK / 8;            // 16B chunks per LDS row
    constexpr int RPS = 512 / BK;          // rows per 1KB gll segment
    constexpr int PASSES = BM * BK / 2048; // gll passes per side
    __shared__ __align__(16) unsigned short As[BM * BK];
    __shared__ __align__(16) unsigned short Bs[BN * BK];
    __shared__ float part[2][BM];

    const int tid  = threadIdx.x;
    const int wave = tid >> 6;
    const int lane = tid & 63;
    const int half = lane >> 5;            // 0,1
    const int l31  = lane & 31;
    const int wm = (wave & 1) * 64;
    const int wn = (wave >> 1) * 64;
    const int m0 = blockIdx.x * BM;
    const int n0 = blockIdx.y * BN;

    // staging geometry: 1KB segments, CH lanes per row, XOR chunk swizzle
    const int lr   = lane / CH;            // row within segment
    const int slot = lane % CH;            // physical 16B chunk slot

    const bool waveDead = (wave >= 2) && (n0 + 64 >= cn);

    float16v acc[2][2];
    #pragma unroll
    for (int i = 0; i < 2; ++i)
        #pragma unroll
        for (int j = 0; j < 2; ++j)
            acc[i][j] = (float16v)(0.f);

    for (int k0 = 0; k0 < K; k0 += BK) {
        #pragma unroll
        for (int p = 0; p < PASSES; ++p) {
            const int seg = wave * PASSES + p;
            const int r   = seg * RPS + lr;
            const int c   = slot ^ (r & (CH - 1));
            const unsigned short* gA = A + (size_t)(m0 + r) * lda + k0 + c * 8;
            unsigned short* lA = As + seg * 512 + lane * 8;
            __builtin_amdgcn_global_load_lds(
                (const __attribute__((address_space(1))) unsigned int*)gA,
                (__attribute__((address_space(3))) unsigned int*)lA, 16, 0, 0);
            if (!waveDead) {
                const unsigned short* gB = Bw + (size_t)(n0 + r) * ldb + k0 + c * 8;
                unsigned short* lB = Bs + seg * 512 + lane * 8;
                __builtin_amdgcn_global_load_lds(
                    (const __attribute__((address_space(1))) unsigned int*)gB,
                    (__attribute__((address_space(3))) unsigned int*)lB, 16, 0, 0);
            }
        }
        __syncthreads();

        if (!waveDead) {
            #pragma unroll
            for (int s = 0; s < BK / 16; ++s) {
                const int gch = s * 2 + half;   // global 16B chunk of fragment
                short8 af[2], bf[2];
                #pragma unroll
                for (int i = 0; i < 2; ++i) {
                    const int row = wm + i * 32 + l31;
                    af[i] = *(const short8*)(As + row * BK
                                             + ((gch ^ (row & (CH - 1))) * 8));
                }
                #pragma unroll
                for (int j = 0; j < 2; ++j) {
                    const int row = wn + j * 32 + l31;
                    bf[j] = *(const short8*)(Bs + row * BK
                                             + ((gch ^ (row & (CH - 1))) * 8));
                }
                #pragma unroll
                for (int i = 0; i < 2; ++i)
                    #pragma unroll
                    for (int j = 0; j < 2; ++j)
                        acc[i][j] = __builtin_amdgcn_mfma_f32_32x32x16_bf16(
                            af[i], bf[j], acc[i][j], 0, 0, 0);
            }
        }
        __syncthreads();
    }

    // epilogue: bias + relu + store (cols < stn); relu'd values kept in acc.
    // Dead waves reach here with acc==0 and bias pad==0 -> store exact 0s,
    // which is what GEMM1 needs in h1's K-padding columns.
    #pragma unroll
    for (int j = 0; j < 2; ++j) {
        const int col = n0 + wn + j * 32 + l31;
        const bool cok = (col < stn);
        const float bv = cok ? bias[col] : 0.f;
        #pragma unroll
        for (int i = 0; i < 2; ++i) {
            #pragma unroll
            for (int reg = 0; reg < 16; ++reg) {
                const int row = m0 + wm + i * 32
                              + (reg & 3) + 8 * (reg >> 2) + 4 * half;
                float v = acc[i][j][reg] + bv;
                v = v > 0.f ? v : 0.f;
                acc[i][j][reg] = v;
                if (cok) {
                    if (OUT_BF16)
                        ((unsigned short*)Cp)[(size_t)row * ldc + col] = f2bf(v);
                    else  // dy never re-read on device
                        __builtin_nontemporal_store(
                            v, ((float*)Cp) + (size_t)row * ldc + col);
                }
            }
        }
    }

    if (FINAL_DOT) {
        const int col0 = n0 + wn + l31;
        const int col1 = col0 + 32;
        const float fwv0 = (col0 < HID) ? fW[FIELD + EMB + col0] : 0.f;
        const float fwv1 = (col1 < HID) ? fW[FIELD + EMB + col1] : 0.f;
        #pragma unroll
        for (int i = 0; i < 2; ++i) {
            #pragma unroll
            for (int reg = 0; reg < 16; ++reg) {
                float s = acc[i][0][reg] * fwv0 + acc[i][1][reg] * fwv1;
                s += __shfl_xor(s, 1, 64);  s += __shfl_xor(s, 2, 64);
                s += __shfl_xor(s, 4, 64);  s += __shfl_xor(s, 8, 64);
                s += __shfl_xor(s, 16, 64);
                if (l31 == 0)
                    part[wn >> 6][wm + i * 32
                                  + (reg & 3) + 8 * (reg >> 2) + 4 * half] = s;
            }
        }
        __syncthreads();
        if (tid < BM)
            atomicAdd(out0 + m0 + tid, part[0][tid] + part[1][tid]);
    }
}

// ---------------------------------------------------------------------------
extern "C" void kernel_launch(void* const* d_in, const int* in_sizes, int n_in,
                              void* d_out, int out_size, void* d_ws, size_t ws_size,
                              hipStream_t stream)
{
    const int*   feat_index = (const int*)d_in[0];
    const float* feat_value = (const float*)d_in[1];
    const float* emb_table  = (const float*)d_in[2];
    const float* bias_table = (const float*)d_in[3];
    const float* W1         = (const float*)d_in[4];
    const float* b1         = (const float*)d_in[5];
    const float* W2         = (const float*)d_in[6];
    const float* b2         = (const float*)d_in[7];
    const float* fW         = (const float*)d_in[8];
    const float* fb         = (const float*)d_in[9];

    float* out = (float*)d_out;
    float* out0 = out;
    float* fo   = out + BATCH;
    float* so   = out + (size_t)BATCH * (1 + FIELD);
    float* dy   = out + (size_t)BATCH * (1 + FIELD + EMB);

    // workspace layout (bf16 element counts; all 16B-aligned):
    unsigned short* emb_ws = (unsigned short*)d_ws;                 // B x 1280
    unsigned short* h1     = emb_ws + (size_t)BATCH * K1P;          // B x 512
    unsigned short* W1b    = h1 + (size_t)BATCH * K2P;              // 512 x 1280
    unsigned short* W2b    = W1b + (size_t)NPAD * K1P;              // 512 x 512
    float*          b1p    = (float*)(W2b + (size_t)NPAD * K2P);    // 512
    float*          b2p    = b1p + NPAD;                            // 512

    const int cvt_blocks = (CVT_ELEMS + 255) / 256;
    prep_kernel<<<GATHER_BLOCKS + cvt_blocks, 256, 0, stream>>>(
        feat_index, feat_value, emb_table, bias_table,
        W1, b1, W2, b2, fW, fb,
        emb_ws, W1b, W2b, b1p, b2p, fo, so, out0);

    dim3 grid_g(BATCH / 128, NPAD / 128);  // 128 x 4
    // GEMM1: h1 = relu(emb @ W1^T + b1) -> bf16 at stride K2P=512.
    // Store all 512 cols (finite zeros in 400..511); compute only cols < 448
    // (cn=448 -> ny=3 waves 2,3 skip MFMA exactly as before).
    gemm_mfma<128, true, false><<<grid_g, 256, 0, stream>>>(
        emb_ws, K1P, W1b, K1P, b1p, h1, K2P, /*stn*/ K2P, /*cn*/ 448, K1P,
        nullptr, nullptr);
    // GEMM2: dy = relu(h1 @ W2^T + b2) -> fp32 (nontemporal) + fused final dot.
    // K=512 (W2b zero-padded cols 400..511), BK=128 -> 4 K-steps vs 7.
    gemm_mfma<128, false, true><<<grid_g, 256, 0, stream>>>(
        h1, K2P, W2b, K2P, b2p, dy, HID, /*stn*/ HID, /*cn*/ HID, K2P,
        fW, out0);
}